// Round 1
// baseline (349.677 us; speedup 1.0000x reference)
//
#include <hip/hip_runtime.h>
#include <stdint.h>

// HydraAttention on MI355X (gfx950).
// Pipeline: cvt(x,Wqkv,Wout)->bf16 | GEMM1 qkv | detect mask layout |
//           rownorm+kv reduce | out = q_hat*kv | GEMM2 -> d_out (fp32)

typedef short  short8  __attribute__((ext_vector_type(8)));
typedef float  floatx4 __attribute__((ext_vector_type(4)));

#define BM 128
#define BN 128
#define BK 32

__device__ __forceinline__ void async16(const void* g, void* l) {
  __builtin_amdgcn_global_load_lds((const __attribute__((address_space(1))) void*)g,
                                   (__attribute__((address_space(3))) void*)l, 16, 0, 0);
}

__device__ __forceinline__ uint16_t f2bf(float f) {  // RNE fp32->bf16
  union { float f; uint32_t u; } x; x.f = f;
  uint32_t u = x.u;
  return (uint16_t)((u + 0x7fffu + ((u >> 16) & 1u)) >> 16);
}
__device__ __forceinline__ float bf2f(uint16_t h) {
  union { uint32_t u; float f; } x; x.u = ((uint32_t)h) << 16; return x.f;
}
__device__ __forceinline__ uint32_t pack2(float a, float b) {
  return (uint32_t)f2bf(a) | ((uint32_t)f2bf(b) << 16);
}
__device__ __forceinline__ void upk8(uint4 u, float* f) {
  f[0]=bf2f((uint16_t)u.x); f[1]=bf2f((uint16_t)(u.x>>16));
  f[2]=bf2f((uint16_t)u.y); f[3]=bf2f((uint16_t)(u.y>>16));
  f[4]=bf2f((uint16_t)u.z); f[5]=bf2f((uint16_t)(u.z>>16));
  f[6]=bf2f((uint16_t)u.w); f[7]=bf2f((uint16_t)(u.w>>16));
}

// ---------------- fp32 -> bf16 convert (8 elems/thread) ----------------
__global__ __launch_bounds__(256) void cvt_bf16(const float* __restrict__ in,
                                                uint16_t* __restrict__ out, int n8) {
  int i = blockIdx.x * blockDim.x + threadIdx.x;
  if (i >= n8) return;
  const float4* p = (const float4*)in;
  float4 a = p[(size_t)i * 2], b = p[(size_t)i * 2 + 1];
  uint4 o;
  o.x = pack2(a.x, a.y); o.y = pack2(a.z, a.w);
  o.z = pack2(b.x, b.y); o.w = pack2(b.z, b.w);
  ((uint4*)out)[i] = o;
}

// ---------------- bf16 GEMM: C[M,N] = A[M,K] @ B[N,K]^T + bias ----------------
// m97 structure: 128x128 tile, BK=32, 4 waves (2x2 of 64x64), 16x16x32 MFMA,
// global_load_lds width=16 staging (wave-uniform LDS base + lane*16).
template <int WRITE_BF16>
__global__ __launch_bounds__(256, 2) void gemm_bt(
    const uint16_t* __restrict__ A, const uint16_t* __restrict__ Bw,
    const float* __restrict__ bias, float* __restrict__ Cf,
    uint16_t* __restrict__ Cb, int M, int N, int K)
{
  __shared__ __align__(16) uint16_t As[BM * BK];
  __shared__ __align__(16) uint16_t Bs[BN * BK];
  const int tid  = threadIdx.x;
  const int wave = tid >> 6, lane = tid & 63;
  const int quad = lane >> 4, r16 = lane & 15;
  const int wm = wave & 1, wn = wave >> 1;
  const int tileM = blockIdx.y * BM, tileN = blockIdx.x * BN;

  // staging: 512 chunks of 16B per tile; chunk c -> row c>>2, k-offset (c&3)*8
  const int c0 = wave * 64 + lane, c1 = c0 + 256;
  const size_t ga0 = (size_t)(tileM + (c0 >> 2)) * K + (c0 & 3) * 8;
  const size_t ga1 = (size_t)(tileM + (c1 >> 2)) * K + (c1 & 3) * 8;
  const size_t gb0 = (size_t)(tileN + (c0 >> 2)) * K + (c0 & 3) * 8;
  const size_t gb1 = (size_t)(tileN + (c1 >> 2)) * K + (c1 & 3) * 8;
  char* lA0 = (char*)As + (wave * 64) * 16;
  char* lA1 = (char*)As + (256 + wave * 64) * 16;
  char* lB0 = (char*)Bs + (wave * 64) * 16;
  char* lB1 = (char*)Bs + (256 + wave * 64) * 16;

  floatx4 acc[4][4];
#pragma unroll
  for (int i = 0; i < 4; i++)
#pragma unroll
    for (int j = 0; j < 4; j++) acc[i][j] = (floatx4){0.f, 0.f, 0.f, 0.f};

  for (int k0 = 0; k0 < K; k0 += BK) {
    async16(A + ga0 + k0, lA0);
    async16(A + ga1 + k0, lA1);
    async16(Bw + gb0 + k0, lB0);
    async16(Bw + gb1 + k0, lB1);
    __syncthreads();

    short8 af[4], bf[4];
#pragma unroll
    for (int mi = 0; mi < 4; mi++)
      af[mi] = *(const short8*)&As[(wm * 64 + mi * 16 + r16) * BK + quad * 8];
#pragma unroll
    for (int ni = 0; ni < 4; ni++)
      bf[ni] = *(const short8*)&Bs[(wn * 64 + ni * 16 + r16) * BK + quad * 8];
#pragma unroll
    for (int mi = 0; mi < 4; mi++)
#pragma unroll
      for (int ni = 0; ni < 4; ni++)
        acc[mi][ni] = __builtin_amdgcn_mfma_f32_16x16x32_bf16(af[mi], bf[ni], acc[mi][ni], 0, 0, 0);
    __syncthreads();
  }

  // Epilogue. C/D layout: col = lane&15, row = quad*4 + reg  [m89/m91 verified]
#pragma unroll
  for (int mi = 0; mi < 4; mi++) {
    int rg = tileM + wm * 64 + mi * 16 + quad * 4;
#pragma unroll
    for (int ni = 0; ni < 4; ni++) {
      int cg = tileN + wn * 64 + ni * 16 + r16;
      float bv = bias[cg];
#pragma unroll
      for (int i = 0; i < 4; i++) {
        float v = acc[mi][ni][i] + bv;
        if (WRITE_BF16) Cb[(size_t)(rg + i) * N + cg] = f2bf(v);
        else            Cf[(size_t)(rg + i) * N + cg] = v;
      }
    }
  }
}

// ---------------- mask layout detection ----------------
// flag=1 -> uint8 layout (some byte at i%4!=0 nonzero); flag=0 -> int32 layout.
__global__ __launch_bounds__(256) void detect_mask(const unsigned char* __restrict__ m,
                                                   int* __restrict__ flag) {
  int i = blockIdx.x * blockDim.x + threadIdx.x;  // 16384 threads over 16384 bytes
  int v = ((i & 3) != 0) ? (int)m[i] : 0;
  unsigned long long b = __ballot(v != 0);
  if ((threadIdx.x & 63) == 0 && b) atomicOr(flag, 1);
}

// ---------------- per-row norms + kv reduction ----------------
// 512 blocks: b = bid>>7, 32 rows/block, 8 rows/wave. Lane owns d in [lane*16, lane*16+16).
__global__ __launch_bounds__(256) void rownorm_kv(
    const uint16_t* __restrict__ qkv, const void* __restrict__ maskbuf,
    const int* __restrict__ flag, float* __restrict__ invq, float* __restrict__ kv)
{
  __shared__ float kvloc[1024];
  const int tid = threadIdx.x;
  for (int i = tid; i < 1024; i += 256) kvloc[i] = 0.f;
  __syncthreads();
  const int wave = tid >> 6, lane = tid & 63;
  const int b = blockIdx.x >> 7;
  const int chunk = blockIdx.x & 127;
  const int isU8 = *flag;
  const unsigned char* m8 = (const unsigned char*)maskbuf;
  const int* m32 = (const int*)maskbuf;

  float kvacc[16];
#pragma unroll
  for (int i = 0; i < 16; i++) kvacc[i] = 0.f;

  const int r0 = b * 4096 + chunk * 32 + wave * 8;
  for (int j = 0; j < 8; j++) {
    int r = r0 + j;
    const uint16_t* rp = qkv + (size_t)r * 3072;
    uint4 q0 = *(const uint4*)(rp + lane * 16);
    uint4 q1 = *(const uint4*)(rp + lane * 16 + 8);
    uint4 k0 = *(const uint4*)(rp + 1024 + lane * 16);
    uint4 k1 = *(const uint4*)(rp + 1024 + lane * 16 + 8);
    uint4 v0 = *(const uint4*)(rp + 2048 + lane * 16);
    uint4 v1 = *(const uint4*)(rp + 2048 + lane * 16 + 8);
    float qf[16], kf[16], vf[16];
    upk8(q0, qf); upk8(q1, qf + 8);
    upk8(k0, kf); upk8(k1, kf + 8);
    upk8(v0, vf); upk8(v1, vf + 8);
    float sq = 0.f, sk = 0.f;
#pragma unroll
    for (int i = 0; i < 16; i++) { sq = fmaf(qf[i], qf[i], sq); sk = fmaf(kf[i], kf[i], sk); }
    for (int off = 32; off; off >>= 1) { sq += __shfl_xor(sq, off); sk += __shfl_xor(sk, off); }
    float rq = rsqrtf(sq), rk = rsqrtf(sk);
    if (lane == 0) invq[r] = rq;
    int masked = isU8 ? (int)m8[r] : m32[r];
    if (!masked) {
#pragma unroll
      for (int i = 0; i < 16; i++) kvacc[i] = fmaf(kf[i] * rk, vf[i], kvacc[i]);
    }
  }
#pragma unroll
  for (int i = 0; i < 16; i++) atomicAdd(&kvloc[lane * 16 + i], kvacc[i]);
  __syncthreads();
  for (int i = tid; i < 1024; i += 256) atomicAdd(&kv[b * 1024 + i], kvloc[i]);
}

// ---------------- out = q_hat * kv[b]  (bf16, 8 elems/thread) ----------------
__global__ __launch_bounds__(256) void scale_q(
    const uint16_t* __restrict__ qkv, const float* __restrict__ invq,
    const float* __restrict__ kv, uint16_t* __restrict__ outb)
{
  int i = blockIdx.x * blockDim.x + threadIdx.x;
  int e = i << 3;
  int r = e >> 10;
  int d = e & 1023;
  int b = r >> 12;
  float s = invq[r];
  uint4 qv = *(const uint4*)(qkv + (size_t)r * 3072 + d);
  const float* kp = kv + (b << 10) + d;
  float qf[8]; upk8(qv, qf);
  uint4 o;
  o.x = pack2(qf[0] * s * kp[0], qf[1] * s * kp[1]);
  o.y = pack2(qf[2] * s * kp[2], qf[3] * s * kp[3]);
  o.z = pack2(qf[4] * s * kp[4], qf[5] * s * kp[5]);
  o.w = pack2(qf[6] * s * kp[6], qf[7] * s * kp[7]);
  *(uint4*)(outb + (size_t)r * 1024 + d) = o;
}

extern "C" void kernel_launch(void* const* d_in, const int* in_sizes, int n_in,
                              void* d_out, int out_size, void* d_ws, size_t ws_size,
                              hipStream_t stream) {
  const float* x     = (const float*)d_in[0];
  const void*  mask  = d_in[1];
  const float* W_qkv = (const float*)d_in[2];
  const float* b_qkv = (const float*)d_in[3];
  const float* W_out = (const float*)d_in[4];
  const float* b_out = (const float*)d_in[5];
  float* out = (float*)d_out;

  const int BT = 4 * 4096;  // 16384 rows
  const int D  = 1024;

  char* ws = (char*)d_ws;
  size_t off = 0;
  auto alloc = [&](size_t bytes) { size_t r = off; off += (bytes + 255) & ~(size_t)255; return r; };
  size_t o_xb   = alloc((size_t)BT * D * 2);        // x bf16; reused as out_bf16
  size_t o_qkvb = alloc((size_t)BT * 3 * D * 2);    // qkv bf16
  size_t o_wq   = alloc((size_t)3 * D * D * 2);     // W_qkv bf16
  size_t o_wo   = alloc((size_t)D * D * 2);         // W_out bf16
  size_t o_kv   = alloc((size_t)4 * D * 4 + 256);   // kv (fp32) + flag
  size_t o_invq = alloc((size_t)BT * 4);            // 1/||q|| per row

  uint16_t* xb   = (uint16_t*)(ws + o_xb);
  uint16_t* qkvb = (uint16_t*)(ws + o_qkvb);
  uint16_t* wq   = (uint16_t*)(ws + o_wq);
  uint16_t* wo   = (uint16_t*)(ws + o_wo);
  float*    kv   = (float*)(ws + o_kv);
  int*      flag = (int*)(ws + o_kv + (size_t)4 * D * 4);
  float*    invq = (float*)(ws + o_invq);
  uint16_t* outb = xb;  // x bf16 dead after GEMM1

  hipMemsetAsync(ws + o_kv, 0, (size_t)4 * D * 4 + 256, stream);
  cvt_bf16<<<dim3(BT * D / 8 / 256), 256, 0, stream>>>(x, xb, BT * D / 8);
  cvt_bf16<<<dim3(3 * D * D / 8 / 256), 256, 0, stream>>>(W_qkv, wq, 3 * D * D / 8);
  cvt_bf16<<<dim3(D * D / 8 / 256), 256, 0, stream>>>(W_out, wo, D * D / 8);
  gemm_bt<1><<<dim3(3 * D / BN, BT / BM), 256, 0, stream>>>(xb, wq, b_qkv, nullptr, qkvb, BT, 3 * D, D);
  detect_mask<<<dim3(64), 256, 0, stream>>>((const unsigned char*)mask, flag);
  rownorm_kv<<<dim3(512), 256, 0, stream>>>(qkvb, mask, flag, invq, kv);
  scale_q<<<dim3(BT * D / 8 / 256), 256, 0, stream>>>(qkvb, invq, kv, outb);
  gemm_bt<0><<<dim3(D / BN, BT / BM), 256, 0, stream>>>(outb, wo, b_out, out, nullptr, BT, D, D);
}

// Round 2
// 342.157 us; speedup vs baseline: 1.0220x; 1.0220x over previous
//
#include <hip/hip_runtime.h>
#include <stdint.h>

// HydraAttention on MI355X (gfx950), R2.
// cvt3(x,Wqkv,Wout)->bf16 | detect mask | GEMM1 qkv (32x32x16 mfma, BK=64,
// swizzled LDS) | rownorm+kv | GEMM2 with fused A = q_hat*kv staging.

typedef short  short8   __attribute__((ext_vector_type(8)));
typedef float  floatx16 __attribute__((ext_vector_type(16)));

#define BM 128
#define BN 128
#define BK 64

__device__ __forceinline__ void async16(const void* g, void* l) {
  __builtin_amdgcn_global_load_lds((const __attribute__((address_space(1))) void*)g,
                                   (__attribute__((address_space(3))) void*)l, 16, 0, 0);
}

__device__ __forceinline__ uint16_t f2bf(float f) {  // RNE fp32->bf16
  union { float f; uint32_t u; } x; x.f = f;
  uint32_t u = x.u;
  return (uint16_t)((u + 0x7fffu + ((u >> 16) & 1u)) >> 16);
}
__device__ __forceinline__ float bf2f(uint16_t h) {
  union { uint32_t u; float f; } x; x.u = ((uint32_t)h) << 16; return x.f;
}
__device__ __forceinline__ uint32_t pack2(float a, float b) {
  return (uint32_t)f2bf(a) | ((uint32_t)f2bf(b) << 16);
}
__device__ __forceinline__ void upk8(uint4 u, float* f) {
  f[0]=bf2f((uint16_t)u.x); f[1]=bf2f((uint16_t)(u.x>>16));
  f[2]=bf2f((uint16_t)u.y); f[3]=bf2f((uint16_t)(u.y>>16));
  f[4]=bf2f((uint16_t)u.z); f[5]=bf2f((uint16_t)(u.z>>16));
  f[6]=bf2f((uint16_t)u.w); f[7]=bf2f((uint16_t)(u.w>>16));
}

// ---------------- fused fp32->bf16 convert of 3 buffers ----------------
__global__ __launch_bounds__(256) void cvt3(
    const float* __restrict__ a, uint16_t* __restrict__ ao, int na,
    const float* __restrict__ b, uint16_t* __restrict__ bo, int nb,
    const float* __restrict__ c, uint16_t* __restrict__ co, int nc) {
  int i = blockIdx.x * 256 + threadIdx.x;
  const float* in; uint16_t* out; int j = i;
  if (j < na) { in = a; out = ao; }
  else {
    j -= na;
    if (j < nb) { in = b; out = bo; }
    else { j -= nb; if (j >= nc) return; in = c; out = co; }
  }
  const float4* p = (const float4*)in;
  float4 u = p[(size_t)j * 2], v = p[(size_t)j * 2 + 1];
  uint4 o;
  o.x = pack2(u.x, u.y); o.y = pack2(u.z, u.w);
  o.z = pack2(v.x, v.y); o.w = pack2(v.z, v.w);
  ((uint4*)out)[j] = o;
}

// ---------------- GEMM1: qkv[M,N] = bf16( A[M,K] @ B[N,K]^T + bias ) -------
// 128x128 tile, BK=64, 4 waves as 2x2 of 64x64, each wave 2x2 of 32x32x16 mfma.
// LDS chunk (16B) for (row,kc): index = row*8 + (kc ^ (row&7))  [XOR swizzle]
// Staging dest chunk L = s*256 + wave*64 + lane -> row = L>>3 = s*32+wave*8+(lane>>3),
// source kc = (lane&7) ^ (lane>>3). Read side: chunkpos = kc ^ (row&7) -> 4 lanes/bank.
__global__ __launch_bounds__(256, 2) void gemm1(
    const uint16_t* __restrict__ A, const uint16_t* __restrict__ Bw,
    const float* __restrict__ bias, uint16_t* __restrict__ Cb,
    int N, int K)
{
  __shared__ __align__(16) uint16_t As[BM * BK];
  __shared__ __align__(16) uint16_t Bs[BN * BK];
  const int tid = threadIdx.x;
  const int wave = tid >> 6, lane = tid & 63;
  const int l31 = lane & 31, khalf = lane >> 5;
  const int wm = wave & 1, wn = wave >> 1;
  const int tileM = blockIdx.y * BM, tileN = blockIdx.x * BN;

  const int srow = wave * 8 + (lane >> 3);
  const int skc  = (lane & 7) ^ (lane >> 3);
  const uint16_t* gA = A  + (size_t)(tileM + srow) * K + skc * 8;
  const uint16_t* gB = Bw + (size_t)(tileN + srow) * K + skc * 8;
  char* lA = (char*)As + wave * 64 * 16;
  char* lB = (char*)Bs + wave * 64 * 16;

  floatx16 acc[2][2];
#pragma unroll
  for (int mi = 0; mi < 2; mi++)
#pragma unroll
    for (int ni = 0; ni < 2; ni++)
#pragma unroll
      for (int r = 0; r < 16; r++) acc[mi][ni][r] = 0.f;

  const int arow0 = wm * 64 + l31;
  const int brow0 = wn * 64 + l31;

  for (int k0 = 0; k0 < K; k0 += BK) {
#pragma unroll
    for (int s = 0; s < 4; s++) {
      async16(gA + k0 + s * 32 * K, lA + s * 4096);
      async16(gB + k0 + s * 32 * K, lB + s * 4096);
    }
    __syncthreads();
#pragma unroll
    for (int ks = 0; ks < 4; ks++) {
      const int kc = khalf + ks * 2;
      short8 af[2], bfr[2];
#pragma unroll
      for (int mi = 0; mi < 2; mi++) {
        int r = arow0 + mi * 32;
        af[mi] = *(const short8*)&As[(r * 8 + (kc ^ (r & 7))) * 8];
      }
#pragma unroll
      for (int ni = 0; ni < 2; ni++) {
        int r = brow0 + ni * 32;
        bfr[ni] = *(const short8*)&Bs[(r * 8 + (kc ^ (r & 7))) * 8];
      }
#pragma unroll
      for (int mi = 0; mi < 2; mi++)
#pragma unroll
        for (int ni = 0; ni < 2; ni++)
          acc[mi][ni] = __builtin_amdgcn_mfma_f32_32x32x16_bf16(af[mi], bfr[ni], acc[mi][ni], 0, 0, 0);
    }
    __syncthreads();
  }

  // C/D layout 32x32: col = lane&31, row = (reg&3) + 8*(reg>>2) + 4*(lane>>5)
#pragma unroll
  for (int mi = 0; mi < 2; mi++) {
    int rbase = tileM + wm * 64 + mi * 32 + 4 * khalf;
#pragma unroll
    for (int ni = 0; ni < 2; ni++) {
      int col = tileN + wn * 64 + ni * 32 + l31;
      float bv = bias[col];
#pragma unroll
      for (int reg = 0; reg < 16; reg++) {
        int row = rbase + (reg & 3) + 8 * (reg >> 2);
        Cb[(size_t)row * N + col] = f2bf(acc[mi][ni][reg] + bv);
      }
    }
  }
}

// ---------------- GEMM2: out[M,N] = (q_hat*kv)[M,K] @ Wout[N,K]^T + bias ----
// A staged on the fly: A[r][d] = bf16( q[r][d] * invq[r] * kv[b][d] ).
__global__ __launch_bounds__(256, 2) void gemm2(
    const uint16_t* __restrict__ qkv, const float* __restrict__ invq,
    const float* __restrict__ kv, const uint16_t* __restrict__ Bw,
    const float* __restrict__ bias, float* __restrict__ Cf,
    int N, int K)
{
  __shared__ __align__(16) uint16_t As[BM * BK];
  __shared__ __align__(16) uint16_t Bs[BN * BK];
  const int tid = threadIdx.x;
  const int wave = tid >> 6, lane = tid & 63;
  const int l31 = lane & 31, khalf = lane >> 5;
  const int wm = wave & 1, wn = wave >> 1;
  const int tileM = blockIdx.y * BM, tileN = blockIdx.x * BN;

  const int srow = wave * 8 + (lane >> 3);
  const int skc  = (lane & 7) ^ (lane >> 3);
  const uint16_t* gB = Bw + (size_t)(tileN + srow) * K + skc * 8;
  char* lB = (char*)Bs + wave * 64 * 16;
  const float* kvb = kv + ((tileM >> 12) << 10);

  float sinv[4];
#pragma unroll
  for (int s = 0; s < 4; s++) sinv[s] = invq[tileM + s * 32 + srow];

  floatx16 acc[2][2];
#pragma unroll
  for (int mi = 0; mi < 2; mi++)
#pragma unroll
    for (int ni = 0; ni < 2; ni++)
#pragma unroll
      for (int r = 0; r < 16; r++) acc[mi][ni][r] = 0.f;

  const int arow0 = wm * 64 + l31;
  const int brow0 = wn * 64 + l31;

  for (int k0 = 0; k0 < K; k0 += BK) {
#pragma unroll
    for (int s = 0; s < 4; s++)
      async16(gB + k0 + s * 32 * K, lB + s * 4096);
#pragma unroll
    for (int s = 0; s < 4; s++) {
      int r = tileM + s * 32 + srow;
      int d = k0 + skc * 8;
      uint4 qv = *(const uint4*)(qkv + (size_t)r * 3072 + d);
      float4 k0v = *(const float4*)(kvb + d);
      float4 k1v = *(const float4*)(kvb + d + 4);
      float qf[8]; upk8(qv, qf);
      float sc = sinv[s];
      uint4 o;
      o.x = pack2(qf[0] * sc * k0v.x, qf[1] * sc * k0v.y);
      o.y = pack2(qf[2] * sc * k0v.z, qf[3] * sc * k0v.w);
      o.z = pack2(qf[4] * sc * k1v.x, qf[5] * sc * k1v.y);
      o.w = pack2(qf[6] * sc * k1v.z, qf[7] * sc * k1v.w);
      *(uint4*)((char*)As + (size_t)(s * 256 + wave * 64 + lane) * 16) = o;
    }
    __syncthreads();
#pragma unroll
    for (int ks = 0; ks < 4; ks++) {
      const int kc = khalf + ks * 2;
      short8 af[2], bfr[2];
#pragma unroll
      for (int mi = 0; mi < 2; mi++) {
        int r = arow0 + mi * 32;
        af[mi] = *(const short8*)&As[(r * 8 + (kc ^ (r & 7))) * 8];
      }
#pragma unroll
      for (int ni = 0; ni < 2; ni++) {
        int r = brow0 + ni * 32;
        bfr[ni] = *(const short8*)&Bs[(r * 8 + (kc ^ (r & 7))) * 8];
      }
#pragma unroll
      for (int mi = 0; mi < 2; mi++)
#pragma unroll
        for (int ni = 0; ni < 2; ni++)
          acc[mi][ni] = __builtin_amdgcn_mfma_f32_32x32x16_bf16(af[mi], bfr[ni], acc[mi][ni], 0, 0, 0);
    }
    __syncthreads();
  }

#pragma unroll
  for (int mi = 0; mi < 2; mi++) {
    int rbase = tileM + wm * 64 + mi * 32 + 4 * khalf;
#pragma unroll
    for (int ni = 0; ni < 2; ni++) {
      int col = tileN + wn * 64 + ni * 32 + l31;
      float bv = bias[col];
#pragma unroll
      for (int reg = 0; reg < 16; reg++) {
        int row = rbase + (reg & 3) + 8 * (reg >> 2);
        Cf[(size_t)row * N + col] = acc[mi][ni][reg] + bv;
      }
    }
  }
}

// ---------------- mask layout detection ----------------
__global__ __launch_bounds__(256) void detect_mask(const unsigned char* __restrict__ m,
                                                   int* __restrict__ flag) {
  int i = blockIdx.x * blockDim.x + threadIdx.x;
  int v = ((i & 3) != 0) ? (int)m[i] : 0;
  unsigned long long b = __ballot(v != 0);
  if ((threadIdx.x & 63) == 0 && b) atomicOr(flag, 1);
}

// ---------------- per-row norms + kv reduction ----------------
__global__ __launch_bounds__(256) void rownorm_kv(
    const uint16_t* __restrict__ qkv, const void* __restrict__ maskbuf,
    const int* __restrict__ flag, float* __restrict__ invq, float* __restrict__ kv)
{
  __shared__ float kvloc[1024];
  const int tid = threadIdx.x;
  for (int i = tid; i < 1024; i += 256) kvloc[i] = 0.f;
  __syncthreads();
  const int wave = tid >> 6, lane = tid & 63;
  const int b = blockIdx.x >> 7;
  const int chunk = blockIdx.x & 127;
  const int isU8 = *flag;
  const unsigned char* m8 = (const unsigned char*)maskbuf;
  const int* m32 = (const int*)maskbuf;

  float kvacc[16];
#pragma unroll
  for (int i = 0; i < 16; i++) kvacc[i] = 0.f;

  const int r0 = b * 4096 + chunk * 32 + wave * 8;
  for (int j = 0; j < 8; j++) {
    int r = r0 + j;
    const uint16_t* rp = qkv + (size_t)r * 3072;
    uint4 q0 = *(const uint4*)(rp + lane * 16);
    uint4 q1 = *(const uint4*)(rp + lane * 16 + 8);
    uint4 k0 = *(const uint4*)(rp + 1024 + lane * 16);
    uint4 k1 = *(const uint4*)(rp + 1024 + lane * 16 + 8);
    uint4 v0 = *(const uint4*)(rp + 2048 + lane * 16);
    uint4 v1 = *(const uint4*)(rp + 2048 + lane * 16 + 8);
    float qf[16], kf[16], vf[16];
    upk8(q0, qf); upk8(q1, qf + 8);
    upk8(k0, kf); upk8(k1, kf + 8);
    upk8(v0, vf); upk8(v1, vf + 8);
    float sq = 0.f, sk = 0.f;
#pragma unroll
    for (int i = 0; i < 16; i++) { sq = fmaf(qf[i], qf[i], sq); sk = fmaf(kf[i], kf[i], sk); }
    for (int off = 32; off; off >>= 1) { sq += __shfl_xor(sq, off); sk += __shfl_xor(sk, off); }
    float rq = rsqrtf(sq), rk = rsqrtf(sk);
    if (lane == 0) invq[r] = rq;
    int masked = isU8 ? (int)m8[r] : m32[r];
    if (!masked) {
#pragma unroll
      for (int i = 0; i < 16; i++) kvacc[i] = fmaf(kf[i] * rk, vf[i], kvacc[i]);
    }
  }
#pragma unroll
  for (int i = 0; i < 16; i++) atomicAdd(&kvloc[lane * 16 + i], kvacc[i]);
  __syncthreads();
  for (int i = tid; i < 1024; i += 256) atomicAdd(&kv[b * 1024 + i], kvloc[i]);
}

extern "C" void kernel_launch(void* const* d_in, const int* in_sizes, int n_in,
                              void* d_out, int out_size, void* d_ws, size_t ws_size,
                              hipStream_t stream) {
  const float* x     = (const float*)d_in[0];
  const void*  mask  = d_in[1];
  const float* W_qkv = (const float*)d_in[2];
  const float* b_qkv = (const float*)d_in[3];
  const float* W_out = (const float*)d_in[4];
  const float* b_out = (const float*)d_in[5];
  float* out = (float*)d_out;

  const int BT = 4 * 4096;  // 16384 rows
  const int D  = 1024;

  char* ws = (char*)d_ws;
  size_t off = 0;
  auto alloc = [&](size_t bytes) { size_t r = off; off += (bytes + 255) & ~(size_t)255; return r; };
  size_t o_xb   = alloc((size_t)BT * D * 2);        // x bf16
  size_t o_qkvb = alloc((size_t)BT * 3 * D * 2);    // qkv bf16
  size_t o_wq   = alloc((size_t)3 * D * D * 2);     // W_qkv bf16
  size_t o_wo   = alloc((size_t)D * D * 2);         // W_out bf16
  size_t o_kv   = alloc((size_t)4 * D * 4 + 256);   // kv (fp32) + flag
  size_t o_invq = alloc((size_t)BT * 4);            // 1/||q|| per row

  uint16_t* xb   = (uint16_t*)(ws + o_xb);
  uint16_t* qkvb = (uint16_t*)(ws + o_qkvb);
  uint16_t* wq   = (uint16_t*)(ws + o_wq);
  uint16_t* wo   = (uint16_t*)(ws + o_wo);
  float*    kv   = (float*)(ws + o_kv);
  int*      flag = (int*)(ws + o_kv + (size_t)4 * D * 4);
  float*    invq = (float*)(ws + o_invq);

  hipMemsetAsync(ws + o_kv, 0, (size_t)4 * D * 4 + 256, stream);
  {
    int na = BT * D / 8, nb = 3 * D * D / 8, nc = D * D / 8;
    int tot = na + nb + nc;
    cvt3<<<dim3((tot + 255) / 256), 256, 0, stream>>>(x, xb, na, W_qkv, wq, nb, W_out, wo, nc);
  }
  detect_mask<<<dim3(64), 256, 0, stream>>>((const unsigned char*)mask, flag);
  gemm1<<<dim3(3 * D / BN, BT / BM), 256, 0, stream>>>(xb, wq, b_qkv, qkvb, 3 * D, D);
  rownorm_kv<<<dim3(512), 256, 0, stream>>>(qkvb, mask, flag, invq, kv);
  gemm2<<<dim3(D / BN, BT / BM), 256, 0, stream>>>(qkvb, invq, kv, wo, b_out, out, D, D);
}